// Round 12
// baseline (861.066 us; speedup 1.0000x reference)
//
#include <hip/hip_runtime.h>
#include <math.h>

#define N_NODES 200000
#define N_EDGES 6400000
#define F_IN 128
#define NH 16
#define BKT_NODES 256   // nodes per bucket
#define NBINS 1024      // hist bins (782 used)
#define NB 782          // buckets = ceil(200000/256)
#define CH 8192         // edges per chunk
#define NCHUNK 782      // ceil(6400000/8192)

// ws layout in 4-byte words
#define OFF_DINV    0            // [200000] float
#define OFF_BCOUNT  200000       // [1024] int
#define OFF_BBASE   201024       // [1024] int
#define OFF_HISTB   202048       // [NCHUNK*1024] int
#define OFF_BASEB   1002816      // [NCHUNK*1024] int
#define OFF_EBUF    1803584      // [E] u32 packed (dst_local<<18)|src
#define OFF_H1B     8203584      // [8N words] bf16 h1b[N][16] (= dinv*h1)
#define OFF_H2B     9803584      // [2N] float h2b (= dinv*h2)

__device__ __forceinline__ unsigned bf16rne(float f) {
    unsigned u = __float_as_uint(f);
    unsigned r = ((u >> 16) & 1u) + 0x7FFFu;
    return (u + r) >> 16;
}
__device__ __forceinline__ float uaf(unsigned u) { return __uint_as_float(u); }

// Wave-uniform int64-vs-int32 detection (int32 pairs read as i64 are OOR w.h.p.)
__device__ __forceinline__ int detect_is32(const void* edges) {
    const long long* e64 = (const long long*)edges;
    long long v = e64[threadIdx.x & 63];
    return __any((v < 0) || (v >= N_NODES)) ? 1 : 0;
}

__global__ __launch_bounds__(1024) void k_init(int* bcount) {
    bcount[threadIdx.x] = 0;
}

// per-chunk 1024-bin histogram (bins = 256-node buckets); persist + global acc
__global__ __launch_bounds__(512) void k_bhist(const void* edges, int* bcount,
                                               int* __restrict__ histB) {
    __shared__ int sH[NBINS];
    int t = threadIdx.x;
    int is32 = detect_is32(edges);
    sH[t] = 0; sH[t + 512] = 0;
    __syncthreads();
    long long e0 = (long long)blockIdx.x * CH;
    int nloc = (int)min((long long)CH, (long long)N_EDGES - e0);
    int n4 = nloc >> 2;
    if (is32) {
        const int4* d4 = (const int4*)((const int*)edges + N_EDGES + e0);
        for (int j = t; j < n4; j += 512) {
            int4 d = d4[j];
            atomicAdd(&sH[d.x >> 8], 1);
            atomicAdd(&sH[d.y >> 8], 1);
            atomicAdd(&sH[d.z >> 8], 1);
            atomicAdd(&sH[d.w >> 8], 1);
        }
    } else {
        const longlong2* d2 = (const longlong2*)((const long long*)edges + N_EDGES + e0);
        for (int j = t; j < n4; j += 512) {
            longlong2 a = d2[2 * j], b = d2[2 * j + 1];
            atomicAdd(&sH[(int)a.x >> 8], 1);
            atomicAdd(&sH[(int)a.y >> 8], 1);
            atomicAdd(&sH[(int)b.x >> 8], 1);
            atomicAdd(&sH[(int)b.y >> 8], 1);
        }
    }
    __syncthreads();
    int* hb = histB + blockIdx.x * NBINS;
    hb[t] = sH[t];
    hb[t + 512] = sH[t + 512];
    if (sH[t]) atomicAdd(&bcount[t], sH[t]);
    if (sH[t + 512]) atomicAdd(&bcount[t + 512], sH[t + 512]);
}

// single block of 512: pair-based exclusive scan of 1024 bins -> bbase
__global__ __launch_bounds__(512) void k_bscan(const int* __restrict__ bcount,
                                               int* __restrict__ bbase) {
    __shared__ int sWsum[8];
    int t = threadIdx.x;
    int c0 = bcount[2 * t], c1 = bcount[2 * t + 1];
    int pairSum = c0 + c1;
    int lane = t & 63, w = t >> 6;
    int v = pairSum;
    for (int off = 1; off < 64; off <<= 1) {
        int nbr = __shfl_up(v, off, 64);
        if (lane >= off) v += nbr;
    }
    if (lane == 63) sWsum[w] = v;
    __syncthreads();
    int add = 0;
    for (int k = 0; k < w; k++) add += sWsum[k];
    int excl = v + add - pairSum;
    bbase[2 * t] = excl;
    bbase[2 * t + 1] = excl + c0;
}

// one block per bucket q: scan histB[blk][q] over blk -> baseB[blk][q]
__global__ __launch_bounds__(256) void k_colscan(const int* __restrict__ histB,
                                                 const int* __restrict__ bbase,
                                                 int* __restrict__ baseB) {
    __shared__ int sW[4];
    __shared__ int sCarry;
    int q = blockIdx.x;
    int t = threadIdx.x;
    int lane = t & 63, w = t >> 6;
    if (t == 0) sCarry = bbase[q];
    __syncthreads();
    for (int c0 = 0; c0 < NCHUNK; c0 += 256) {
        int blk = c0 + t;
        int orig = (blk < NCHUNK) ? histB[blk * NBINS + q] : 0;
        int v = orig;
        for (int off = 1; off < 64; off <<= 1) {
            int nbr = __shfl_up(v, off, 64);
            if (lane >= off) v += nbr;
        }
        if (lane == 63) sW[w] = v;
        __syncthreads();
        int add = sCarry;
        for (int k = 0; k < w; k++) add += sW[k];
        if (blk < NCHUNK) baseB[blk * NBINS + q] = add + v - orig;
        __syncthreads();
        if (t == 255) sCarry = add + v;
        __syncthreads();
    }
}

// single edge read; LDS rank-scatter to bucket order; coalesced copy-out
__global__ __launch_bounds__(512) void k_bscatter(const void* edges,
                                                  const int* __restrict__ histB,
                                                  const int* __restrict__ baseB,
                                                  unsigned* __restrict__ ebuf) {
    __shared__ unsigned sS[CH];     // 32 KB sorted packed edges
    __shared__ int sStart[NBINS];
    __shared__ int sCur[NBINS];
    __shared__ int sGb[NBINS];
    __shared__ int sWsum[8];
    int t = threadIdx.x;
    int is32 = detect_is32(edges);
    long long e0 = (long long)blockIdx.x * CH;
    int nloc = (int)min((long long)CH, (long long)N_EDGES - e0);
    int n4 = nloc >> 2;
    const int* hb = histB + blockIdx.x * NBINS;
    const int* bb = baseB + blockIdx.x * NBINS;
    int h0 = hb[2 * t], h1 = hb[2 * t + 1];
    int g0 = bb[2 * t], g1 = bb[2 * t + 1];
    int pairSum = h0 + h1;
    int lane = t & 63, w = t >> 6;
    int v = pairSum;
    for (int off = 1; off < 64; off <<= 1) {
        int nbr = __shfl_up(v, off, 64);
        if (lane >= off) v += nbr;
    }
    if (lane == 63) sWsum[w] = v;
    __syncthreads();
    int add = 0;
    for (int k = 0; k < w; k++) add += sWsum[k];
    int excl = v + add - pairSum;
    sStart[2 * t] = excl;          sStart[2 * t + 1] = excl + h0;
    sCur[2 * t] = excl;            sCur[2 * t + 1] = excl + h0;
    sGb[2 * t] = g0 - excl;        sGb[2 * t + 1] = g1 - (excl + h0);
    __syncthreads();
    if (is32) {
        const int4* s4 = (const int4*)((const int*)edges + e0);
        const int4* d4 = (const int4*)((const int*)edges + N_EDGES + e0);
        for (int j = t; j < n4; j += 512) {
            int4 s = s4[j];
            int4 d = d4[j];
            int r;
            r = atomicAdd(&sCur[d.x >> 8], 1); sS[r] = (unsigned)(((d.x & 255) << 18) | s.x);
            r = atomicAdd(&sCur[d.y >> 8], 1); sS[r] = (unsigned)(((d.y & 255) << 18) | s.y);
            r = atomicAdd(&sCur[d.z >> 8], 1); sS[r] = (unsigned)(((d.z & 255) << 18) | s.z);
            r = atomicAdd(&sCur[d.w >> 8], 1); sS[r] = (unsigned)(((d.w & 255) << 18) | s.w);
        }
    } else {
        const longlong2* s2 = (const longlong2*)((const long long*)edges + e0);
        const longlong2* d2 = (const longlong2*)((const long long*)edges + N_EDGES + e0);
        for (int j = t; j < n4; j += 512) {
            longlong2 sa = s2[2 * j], sb = s2[2 * j + 1];
            longlong2 da = d2[2 * j], db = d2[2 * j + 1];
            int s0 = (int)sa.x, s1 = (int)sa.y, s2i = (int)sb.x, s3 = (int)sb.y;
            int d0 = (int)da.x, d1 = (int)da.y, d2i = (int)db.x, d3 = (int)db.y;
            int r;
            r = atomicAdd(&sCur[d0 >> 8], 1); sS[r] = (unsigned)(((d0 & 255) << 18) | s0);
            r = atomicAdd(&sCur[d1 >> 8], 1); sS[r] = (unsigned)(((d1 & 255) << 18) | s1);
            r = atomicAdd(&sCur[d2i >> 8], 1); sS[r] = (unsigned)(((d2i & 255) << 18) | s2i);
            r = atomicAdd(&sCur[d3 >> 8], 1); sS[r] = (unsigned)(((d3 & 255) << 18) | s3);
        }
    }
    __syncthreads();
    for (int j = t; j < nloc; j += 512) {
        int lo = 0;
#pragma unroll
        for (int step = 512; step > 0; step >>= 1) {
            int mid = lo + step;
            if (mid < NBINS && sStart[mid] <= j) lo = mid;
        }
        ebuf[sGb[lo] + j] = sS[j];
    }
}

// per bucket: per-node degree from packed dst_local -> dinv
__global__ __launch_bounds__(512) void k_degb(const unsigned* __restrict__ ebuf,
                                              const int* __restrict__ bbase,
                                              float* __restrict__ dinv) {
    __shared__ int sCnt[BKT_NODES];
    int b = blockIdx.x, t = threadIdx.x;
    int base = bbase[b];
    int cnt = bbase[b + 1] - base;
    if (t < BKT_NODES) sCnt[t] = 0;
    __syncthreads();
    for (int j = t; j < cnt; j += 512)
        atomicAdd(&sCnt[ebuf[base + j] >> 18], 1);
    __syncthreads();
    if (t < BKT_NODES) {
        int node = b * BKT_NODES + t;
        if (node < N_NODES) dinv[node] = rsqrtf((float)sCnt[t] + 1.0f);
    }
}

// h1b = dinv * (x @ W1), bf16 [N][16]. 4 lanes/row, k-phased contiguous 64 B.
__global__ __launch_bounds__(256) void k_gemm1(const float* __restrict__ x,
                                               const float* __restrict__ W1,
                                               const float* __restrict__ dinv,
                                               unsigned short* __restrict__ h1b) {
    __shared__ float sWt[NH * F_IN];   // [c][k]
    int t = threadIdx.x;
    for (int q = t; q < 512; q += 256) {
        float4 wv = ((const float4*)W1)[q];
        int k = q >> 2, c0 = (q & 3) * 4;
        sWt[(c0 + 0) * F_IN + k] = wv.x;
        sWt[(c0 + 1) * F_IN + k] = wv.y;
        sWt[(c0 + 2) * F_IN + k] = wv.z;
        sWt[(c0 + 3) * F_IN + k] = wv.w;
    }
    __syncthreads();
    int r = blockIdx.x * 64 + (t >> 2);
    int l = t & 3;
    if (r >= N_NODES) return;
    float acc[NH];
#pragma unroll
    for (int c = 0; c < NH; c++) acc[c] = 0.f;
    const float4* xr = (const float4*)(x + (size_t)r * F_IN);
#pragma unroll
    for (int s = 0; s < 8; s++) {
        float4 xv = xr[s * 4 + l];
        int k0 = s * 16 + l * 4;
#pragma unroll
        for (int c = 0; c < NH; c++) {
            float4 wv = *(const float4*)&sWt[c * F_IN + k0];
            acc[c] += xv.x * wv.x + xv.y * wv.y + xv.z * wv.z + xv.w * wv.w;
        }
    }
#pragma unroll
    for (int c = 0; c < NH; c++) {
        acc[c] += __shfl_xor(acc[c], 1, 4);
        acc[c] += __shfl_xor(acc[c], 2, 4);
    }
    float di = dinv[r];
    unsigned p0 = bf16rne(acc[l * 4 + 0] * di) | (bf16rne(acc[l * 4 + 1] * di) << 16);
    unsigned p1 = bf16rne(acc[l * 4 + 2] * di) | (bf16rne(acc[l * 4 + 3] * di) << 16);
    *(uint2*)(h1b + (size_t)r * NH + l * 4) = make_uint2(p0, p1);
}

__device__ __forceinline__ void acc_edge(float* row, uint4 lo, uint4 hi) {
    atomicAdd(row + 0,  uaf(lo.x << 16)); atomicAdd(row + 1,  uaf(lo.x & 0xFFFF0000u));
    atomicAdd(row + 2,  uaf(lo.y << 16)); atomicAdd(row + 3,  uaf(lo.y & 0xFFFF0000u));
    atomicAdd(row + 4,  uaf(lo.z << 16)); atomicAdd(row + 5,  uaf(lo.z & 0xFFFF0000u));
    atomicAdd(row + 6,  uaf(lo.w << 16)); atomicAdd(row + 7,  uaf(lo.w & 0xFFFF0000u));
    atomicAdd(row + 8,  uaf(hi.x << 16)); atomicAdd(row + 9,  uaf(hi.x & 0xFFFF0000u));
    atomicAdd(row + 10, uaf(hi.y << 16)); atomicAdd(row + 11, uaf(hi.y & 0xFFFF0000u));
    atomicAdd(row + 12, uaf(hi.z << 16)); atomicAdd(row + 13, uaf(hi.z & 0xFFFF0000u));
    atomicAdd(row + 14, uaf(hi.w << 16)); atomicAdd(row + 15, uaf(hi.w & 0xFFFF0000u));
}

// fused layer-1 gather: per bucket, LDS f32 accumulate (stride 17, conflict-free),
// then per node: + self + b1, relu, @W2, h2b = di*h2.
__global__ __launch_bounds__(512) void k_gather1f(const unsigned* __restrict__ ebuf,
                                                  const int* __restrict__ bbase,
                                                  const float* __restrict__ dinv,
                                                  const unsigned short* __restrict__ h1b,
                                                  const float* __restrict__ b1,
                                                  const float* __restrict__ W2,
                                                  float* __restrict__ h2b) {
    __shared__ float sAgg[BKT_NODES * 17];
    int b = blockIdx.x, t = threadIdx.x;
    int base = bbase[b];
    int cnt = bbase[b + 1] - base;
    for (int j = t; j < BKT_NODES * 17; j += 512) sAgg[j] = 0.f;
    __syncthreads();
    int j = t;
    for (; j + 512 < cnt; j += 1024) {
        unsigned p0 = ebuf[base + j];
        unsigned p1 = ebuf[base + j + 512];
        const uint4* hp0 = (const uint4*)(h1b + ((size_t)(p0 & 0x3FFFF) << 4));
        const uint4* hp1 = (const uint4*)(h1b + ((size_t)(p1 & 0x3FFFF) << 4));
        uint4 lo0 = hp0[0], hi0 = hp0[1];
        uint4 lo1 = hp1[0], hi1 = hp1[1];
        acc_edge(&sAgg[(p0 >> 18) * 17], lo0, hi0);
        acc_edge(&sAgg[(p1 >> 18) * 17], lo1, hi1);
    }
    for (; j < cnt; j += 512) {
        unsigned p = ebuf[base + j];
        const uint4* hp = (const uint4*)(h1b + ((size_t)(p & 0x3FFFF) << 4));
        uint4 lo = hp[0], hi = hp[1];
        acc_edge(&sAgg[(p >> 18) * 17], lo, hi);
    }
    __syncthreads();
    if (t < BKT_NODES) {
        int node = b * BKT_NODES + t;
        if (node < N_NODES) {
            float di = dinv[node];
            const uint4* hp = (const uint4*)(h1b + ((size_t)node << 4));
            uint4 lo = hp[0], hi = hp[1];
            float sf[16];
            sf[0] = uaf(lo.x << 16);  sf[1] = uaf(lo.x & 0xFFFF0000u);
            sf[2] = uaf(lo.y << 16);  sf[3] = uaf(lo.y & 0xFFFF0000u);
            sf[4] = uaf(lo.z << 16);  sf[5] = uaf(lo.z & 0xFFFF0000u);
            sf[6] = uaf(lo.w << 16);  sf[7] = uaf(lo.w & 0xFFFF0000u);
            sf[8] = uaf(hi.x << 16);  sf[9] = uaf(hi.x & 0xFFFF0000u);
            sf[10] = uaf(hi.y << 16); sf[11] = uaf(hi.y & 0xFFFF0000u);
            sf[12] = uaf(hi.z << 16); sf[13] = uaf(hi.z & 0xFFFF0000u);
            sf[14] = uaf(hi.w << 16); sf[15] = uaf(hi.w & 0xFFFF0000u);
            const float* a = &sAgg[t * 17];
            float p0 = 0.f, p1 = 0.f;
#pragma unroll
            for (int f = 0; f < 16; f++) {
                float rv = fmaxf(di * (a[f] + sf[f]) + b1[f], 0.f);
                p0 += rv * W2[f * 2 + 0];
                p1 += rv * W2[f * 2 + 1];
            }
            float2 hv;
            hv.x = di * p0;
            hv.y = di * p1;
            *(float2*)(h2b + (size_t)node * 2) = hv;
        }
    }
}

// fused layer-2 gather: per bucket LDS accumulate (stride 3), log_softmax out.
__global__ __launch_bounds__(512) void k_gather2f(const unsigned* __restrict__ ebuf,
                                                  const int* __restrict__ bbase,
                                                  const float* __restrict__ dinv,
                                                  const float* __restrict__ h2b,
                                                  const float* __restrict__ b2,
                                                  float* __restrict__ out) {
    __shared__ float sA[BKT_NODES * 3];
    int b = blockIdx.x, t = threadIdx.x;
    int base = bbase[b];
    int cnt = bbase[b + 1] - base;
    for (int j = t; j < BKT_NODES * 3; j += 512) sA[j] = 0.f;
    __syncthreads();
    int j = t;
    for (; j + 512 < cnt; j += 1024) {
        unsigned p0 = ebuf[base + j];
        unsigned p1 = ebuf[base + j + 512];
        float2 h0 = *(const float2*)(h2b + ((size_t)(p0 & 0x3FFFF) << 1));
        float2 h1 = *(const float2*)(h2b + ((size_t)(p1 & 0x3FFFF) << 1));
        atomicAdd(&sA[(p0 >> 18) * 3 + 0], h0.x);
        atomicAdd(&sA[(p0 >> 18) * 3 + 1], h0.y);
        atomicAdd(&sA[(p1 >> 18) * 3 + 0], h1.x);
        atomicAdd(&sA[(p1 >> 18) * 3 + 1], h1.y);
    }
    for (; j < cnt; j += 512) {
        unsigned p = ebuf[base + j];
        float2 hv = *(const float2*)(h2b + ((size_t)(p & 0x3FFFF) << 1));
        atomicAdd(&sA[(p >> 18) * 3 + 0], hv.x);
        atomicAdd(&sA[(p >> 18) * 3 + 1], hv.y);
    }
    __syncthreads();
    if (t < BKT_NODES) {
        int node = b * BKT_NODES + t;
        if (node < N_NODES) {
            float di = dinv[node];
            float2 hs = *(const float2*)(h2b + (size_t)node * 2);
            float f0 = di * (sA[t * 3 + 0] + hs.x) + b2[0];
            float f1 = di * (sA[t * 3 + 1] + hs.y) + b2[1];
            float m = fmaxf(f0, f1);
            float lse = m + logf(expf(f0 - m) + expf(f1 - m));
            out[(size_t)node * 2 + 0] = f0 - lse;
            out[(size_t)node * 2 + 1] = f1 - lse;
        }
    }
}

extern "C" void kernel_launch(void* const* d_in, const int* in_sizes, int n_in,
                              void* d_out, int out_size, void* d_ws, size_t ws_size,
                              hipStream_t stream) {
    const float* x  = (const float*)d_in[0];
    const void*  ei = d_in[1];
    const float* W1 = (const float*)d_in[2];
    const float* b1 = (const float*)d_in[3];
    const float* W2 = (const float*)d_in[4];
    const float* b2 = (const float*)d_in[5];

    int*            wsw       = (int*)d_ws;
    float*          dinv      = (float*)(wsw + OFF_DINV);
    int*            bcount    = wsw + OFF_BCOUNT;
    int*            bbase     = wsw + OFF_BBASE;
    int*            histB     = wsw + OFF_HISTB;
    int*            baseB     = wsw + OFF_BASEB;
    unsigned*       ebuf      = (unsigned*)(wsw + OFF_EBUF);
    unsigned short* h1b       = (unsigned short*)(wsw + OFF_H1B);
    float*          h2b       = (float*)(wsw + OFF_H2B);
    float*          out       = (float*)d_out;

    k_init<<<1, 1024, 0, stream>>>(bcount);
    k_bhist<<<NCHUNK, 512, 0, stream>>>(ei, bcount, histB);
    k_bscan<<<1, 512, 0, stream>>>(bcount, bbase);
    k_colscan<<<NBINS, 256, 0, stream>>>(histB, bbase, baseB);
    k_bscatter<<<NCHUNK, 512, 0, stream>>>(ei, histB, baseB, ebuf);
    k_degb<<<NB, 512, 0, stream>>>(ebuf, bbase, dinv);
    k_gemm1<<<(N_NODES + 63) / 64, 256, 0, stream>>>(x, W1, dinv, h1b);
    k_gather1f<<<NB, 512, 0, stream>>>(ebuf, bbase, dinv, h1b, b1, W2, h2b);
    k_gather2f<<<NB, 512, 0, stream>>>(ebuf, bbase, dinv, h2b, b2, out);
}

// Round 13
// 247.482 us; speedup vs baseline: 3.4793x; 3.4793x over previous
//
#include <hip/hip_runtime.h>
#include <math.h>

#define N_NODES 200000
#define N_EDGES 6400000
#define F_IN 128
#define NH 16
#define BKT_NODES 512   // nodes per bucket
#define NB 391          // bsort blocks = ceil(200000/512)
#define CH 8192         // edges per chunk
#define NCHUNK 782      // ceil(6400000/8192)
#define BKT_CAP 17408   // LDS stage cap per bucket (mean 16384, +8 sigma)

// ws layout in 4-byte words. ebuf (packed edges) is reused in-place as csr_src.
#define OFF_DINV    0            // [N] float
#define OFF_ROW     200000       // [N+1] int
#define OFF_BCOUNT  400004       // [512] int
#define OFF_BBASE   400516       // [512] int
#define OFF_HISTB   401028       // [NCHUNK*512] int  per-block bucket histograms
#define OFF_BASEB   801412       // [NCHUNK*512] int  per-block global bucket bases
#define OFF_EBUF    1201796      // [E] u32 packed (dst_local<<18)|src ; later csr_src
#define OFF_H1B     7601796      // [8N words] bf16 h1b[N][16] (= dinv*h1)
#define OFF_H2B     9201796      // [2N] float h2b (= dinv*h2)

__device__ __forceinline__ unsigned bf16rne(float f) {
    unsigned u = __float_as_uint(f);
    unsigned r = ((u >> 16) & 1u) + 0x7FFFu;
    return (u + r) >> 16;
}

// Wave-uniform int64-vs-int32 detection: read first 64 qwords; if edges are
// int32 pairs, reinterpreted i64 values land outside [0, N_NODES) w.h.p.
__device__ __forceinline__ int detect_is32(const void* edges) {
    const long long* e64 = (const long long*)edges;
    long long v = e64[threadIdx.x & 63];
    return __any((v < 0) || (v >= N_NODES)) ? 1 : 0;
}

__global__ __launch_bounds__(512) void k_init(int* bcount) {
    bcount[threadIdx.x] = 0;
}

// per-chunk 512-bin histogram; persists per-block hist AND accumulates global.
// 512 threads (R12-validated): latency-bound loop needs the wave count.
__global__ __launch_bounds__(512) void k_bhist(const void* edges, int* bcount,
                                               int* __restrict__ histB) {
    __shared__ int sH[512];
    int t = threadIdx.x;
    int is32 = detect_is32(edges);
    sH[t] = 0;
    __syncthreads();
    long long e0 = (long long)blockIdx.x * CH;
    int nloc = (int)min((long long)CH, (long long)N_EDGES - e0);
    int n4 = nloc >> 2;
    if (is32) {
        const int4* d4 = (const int4*)((const int*)edges + N_EDGES + e0);
        for (int j = t; j < n4; j += 512) {
            int4 d = d4[j];
            atomicAdd(&sH[d.x >> 9], 1);
            atomicAdd(&sH[d.y >> 9], 1);
            atomicAdd(&sH[d.z >> 9], 1);
            atomicAdd(&sH[d.w >> 9], 1);
        }
    } else {
        const longlong2* d2 = (const longlong2*)((const long long*)edges + N_EDGES + e0);
        for (int j = t; j < n4; j += 512) {
            longlong2 a = d2[2 * j], b = d2[2 * j + 1];
            atomicAdd(&sH[(int)a.x >> 9], 1);
            atomicAdd(&sH[(int)a.y >> 9], 1);
            atomicAdd(&sH[(int)b.x >> 9], 1);
            atomicAdd(&sH[(int)b.y >> 9], 1);
        }
    }
    __syncthreads();
    histB[blockIdx.x * 512 + t] = sH[t];
    if (sH[t]) atomicAdd(&bcount[t], sH[t]);
}

// single block of 512: exclusive scan bcount -> bbase; row_start[N]=E
__global__ __launch_bounds__(512) void k_bscan(const int* __restrict__ bcount,
                                               int* __restrict__ bbase,
                                               int* __restrict__ row_start) {
    __shared__ int sWsum[8];
    int t = threadIdx.x;
    int c = bcount[t];
    int lane = t & 63, w = t >> 6;
    int v = c;
    for (int off = 1; off < 64; off <<= 1) {
        int nbr = __shfl_up(v, off, 64);
        if (lane >= off) v += nbr;
    }
    if (lane == 63) sWsum[w] = v;
    __syncthreads();
    int add = 0;
    for (int k = 0; k < w; k++) add += sWsum[k];
    int excl = v + add - c;
    bbase[t] = excl;
    if (t == 0) row_start[N_NODES] = N_EDGES;
}

// one block per bucket q: prefix-scan histB[blk][q] over blk -> per-block
// global write base baseB[blk][q] = bbase[q] + sum_{b'<blk} histB[b'][q]
__global__ __launch_bounds__(256) void k_colscan(const int* __restrict__ histB,
                                                 const int* __restrict__ bbase,
                                                 int* __restrict__ baseB) {
    __shared__ int sW[4];
    __shared__ int sCarry;
    int q = blockIdx.x;
    int t = threadIdx.x;
    int lane = t & 63, w = t >> 6;
    if (t == 0) sCarry = bbase[q];
    __syncthreads();
    for (int c0 = 0; c0 < NCHUNK; c0 += 256) {
        int blk = c0 + t;
        int orig = (blk < NCHUNK) ? histB[blk * 512 + q] : 0;
        int v = orig;
        for (int off = 1; off < 64; off <<= 1) {
            int nbr = __shfl_up(v, off, 64);
            if (lane >= off) v += nbr;
        }
        if (lane == 63) sW[w] = v;
        __syncthreads();
        int add = sCarry;
        for (int k = 0; k < w; k++) add += sW[k];
        if (blk < NCHUNK) baseB[blk * 512 + q] = add + v - orig;
        __syncthreads();
        if (t == 255) sCarry = add + v;
        __syncthreads();
    }
}

// single edge read; local starts from histB; LDS rank-scatter; coalesced
// copy-out via baseB. 512 threads (R12-validated occupancy fix).
__global__ __launch_bounds__(512) void k_bscatter(const void* edges,
                                                  const int* __restrict__ histB,
                                                  const int* __restrict__ baseB,
                                                  unsigned* __restrict__ ebuf) {
    __shared__ unsigned sS[CH];    // 32 KB sorted packed edges
    __shared__ int sStart[512];    // local exclusive starts
    __shared__ int sCur[512];      // rank cursors
    __shared__ int sGb[512];       // baseB[q] - sStart[q]  (copy-out fold)
    __shared__ int sWsum[8];
    int t = threadIdx.x;
    int is32 = detect_is32(edges);
    long long e0 = (long long)blockIdx.x * CH;
    int nloc = (int)min((long long)CH, (long long)N_EDGES - e0);
    int n4 = nloc >> 2;
    int h = histB[blockIdx.x * 512 + t];
    int g = baseB[blockIdx.x * 512 + t];
    int lane = t & 63, w = t >> 6;
    int v = h;
    for (int off = 1; off < 64; off <<= 1) {
        int nbr = __shfl_up(v, off, 64);
        if (lane >= off) v += nbr;
    }
    if (lane == 63) sWsum[w] = v;
    __syncthreads();
    int add = 0;
    for (int k = 0; k < w; k++) add += sWsum[k];
    int excl = v + add - h;
    sStart[t] = excl;
    sCur[t] = excl;
    sGb[t] = g - excl;
    __syncthreads();
    // single edge pass: rank-scatter into LDS (sorted by bucket)
    if (is32) {
        const int4* s4 = (const int4*)((const int*)edges + e0);
        const int4* d4 = (const int4*)((const int*)edges + N_EDGES + e0);
        for (int j = t; j < n4; j += 512) {
            int4 s = s4[j];
            int4 d = d4[j];
            int r;
            r = atomicAdd(&sCur[d.x >> 9], 1); sS[r] = (unsigned)(((d.x & 511) << 18) | s.x);
            r = atomicAdd(&sCur[d.y >> 9], 1); sS[r] = (unsigned)(((d.y & 511) << 18) | s.y);
            r = atomicAdd(&sCur[d.z >> 9], 1); sS[r] = (unsigned)(((d.z & 511) << 18) | s.z);
            r = atomicAdd(&sCur[d.w >> 9], 1); sS[r] = (unsigned)(((d.w & 511) << 18) | s.w);
        }
    } else {
        const longlong2* s2 = (const longlong2*)((const long long*)edges + e0);
        const longlong2* d2 = (const longlong2*)((const long long*)edges + N_EDGES + e0);
        for (int j = t; j < n4; j += 512) {
            longlong2 sa = s2[2 * j], sb = s2[2 * j + 1];
            longlong2 da = d2[2 * j], db = d2[2 * j + 1];
            int s0 = (int)sa.x, s1 = (int)sa.y, s2i = (int)sb.x, s3 = (int)sb.y;
            int d0 = (int)da.x, d1 = (int)da.y, d2i = (int)db.x, d3 = (int)db.y;
            int r;
            r = atomicAdd(&sCur[d0 >> 9], 1); sS[r] = (unsigned)(((d0 & 511) << 18) | s0);
            r = atomicAdd(&sCur[d1 >> 9], 1); sS[r] = (unsigned)(((d1 & 511) << 18) | s1);
            r = atomicAdd(&sCur[d2i >> 9], 1); sS[r] = (unsigned)(((d2i & 511) << 18) | s2i);
            r = atomicAdd(&sCur[d3 >> 9], 1); sS[r] = (unsigned)(((d3 & 511) << 18) | s3);
        }
    }
    __syncthreads();
    // coalesced copy-out; rightmost bucket with sStart <= j via binary search
    for (int j = t; j < nloc; j += 512) {
        int lo = 0;
#pragma unroll
        for (int step = 256; step > 0; step >>= 1) {
            int mid = lo + step;
            if (mid < 512 && sStart[mid] <= j) lo = mid;
        }
        ebuf[sGb[lo] + j] = sS[j];
    }
}

// one block per 512-node bucket: stage, 512-bin count+scan -> row_start/dinv,
// ranked scatter writes csr_src IN PLACE over ebuf.
__global__ __launch_bounds__(512) void k_bsort(unsigned* ebuf,
                                               const int* __restrict__ bbase,
                                               int* __restrict__ row_start,
                                               float* __restrict__ dinv) {
    __shared__ unsigned sE[BKT_CAP];
    __shared__ int sH[512];
    __shared__ int sWsum[8];
    int b = blockIdx.x, t = threadIdx.x;
    int base = bbase[b];
    int cnt = bbase[b + 1] - base;
    int cap = cnt < BKT_CAP ? cnt : BKT_CAP;
    for (int j = t; j < cap; j += 512) sE[j] = ebuf[base + j];
    sH[t] = 0;
    __syncthreads();
    for (int j = t; j < cnt; j += 512) {
        unsigned p = (j < cap) ? sE[j] : ebuf[base + j];
        atomicAdd(&sH[p >> 18], 1);
    }
    __syncthreads();
    int h = sH[t];
    int lane = t & 63, w = t >> 6;
    int v = h;
    for (int off = 1; off < 64; off <<= 1) {
        int nbr = __shfl_up(v, off, 64);
        if (lane >= off) v += nbr;
    }
    if (lane == 63) sWsum[w] = v;
    __syncthreads();
    int add = 0;
    for (int k = 0; k < w; k++) add += sWsum[k];
    int excl = v + add - h;
    int node = b * BKT_NODES + t;
    if (node < N_NODES) {
        row_start[node] = base + excl;
        dinv[node] = rsqrtf((float)h + 1.0f);
    }
    __syncthreads();
    sH[t] = excl;
    __syncthreads();
    for (int j = t; j < cnt; j += 512) {
        unsigned p = (j < cap) ? sE[j] : ebuf[base + j];
        int pos = atomicAdd(&sH[p >> 18], 1);
        ebuf[base + pos] = p & 0x3FFFF;
    }
}

// h1b = dinv * (x @ W1), bf16 [N][16]. 4 lanes per row, k-phased: each 4-lane
// group issues contiguous 64 B per step -> every byte of x fetched exactly once.
__global__ __launch_bounds__(256) void k_gemm1(const float* __restrict__ x,
                                               const float* __restrict__ W1,
                                               const float* __restrict__ dinv,
                                               unsigned short* __restrict__ h1b) {
    __shared__ float sWt[NH * F_IN];   // [c][k]
    int t = threadIdx.x;
    for (int q = t; q < 512; q += 256) {
        float4 wv = ((const float4*)W1)[q];
        int k = q >> 2, c0 = (q & 3) * 4;
        sWt[(c0 + 0) * F_IN + k] = wv.x;
        sWt[(c0 + 1) * F_IN + k] = wv.y;
        sWt[(c0 + 2) * F_IN + k] = wv.z;
        sWt[(c0 + 3) * F_IN + k] = wv.w;
    }
    __syncthreads();
    int r = blockIdx.x * 64 + (t >> 2);
    int l = t & 3;
    if (r >= N_NODES) return;
    float acc[NH];
#pragma unroll
    for (int c = 0; c < NH; c++) acc[c] = 0.f;
    const float4* xr = (const float4*)(x + (size_t)r * F_IN);
#pragma unroll
    for (int s = 0; s < 8; s++) {
        float4 xv = xr[s * 4 + l];          // row bytes [s*64 + l*16, +16)
        int k0 = s * 16 + l * 4;
#pragma unroll
        for (int c = 0; c < NH; c++) {
            float4 wv = *(const float4*)&sWt[c * F_IN + k0];
            acc[c] += xv.x * wv.x + xv.y * wv.y + xv.z * wv.z + xv.w * wv.w;
        }
    }
#pragma unroll
    for (int c = 0; c < NH; c++) {
        acc[c] += __shfl_xor(acc[c], 1, 4);
        acc[c] += __shfl_xor(acc[c], 2, 4);
    }
    float di = dinv[r];
    unsigned p0 = bf16rne(acc[l * 4 + 0] * di) | (bf16rne(acc[l * 4 + 1] * di) << 16);
    unsigned p1 = bf16rne(acc[l * 4 + 2] * di) | (bf16rne(acc[l * 4 + 3] * di) << 16);
    *(uint2*)(h1b + (size_t)r * NH + l * 4) = make_uint2(p0, p1);
}

// gather1: 16 lanes/node = 8 edge-slots x 2 feature-halves; uint4 (16 B) per
// lane = one 32 B request per edge; 2x unrolled for MLP (R11-validated).
__global__ __launch_bounds__(256) void k_gather1(const int* __restrict__ row_start,
                                                 const int* __restrict__ csr_src,
                                                 const float* __restrict__ dinv,
                                                 const unsigned short* __restrict__ h1b,
                                                 const float* __restrict__ b1,
                                                 const float* __restrict__ W2,
                                                 float* __restrict__ h2b) {
    int t = threadIdx.x;
    int i = blockIdx.x * 16 + (t >> 4);
    int hf = t & 1;           // feature half: feats 0-7 or 8-15
    int slot = (t >> 1) & 7;  // 8 edge slots
    int start = row_start[i];
    int end = row_start[i + 1];
    float di = dinv[i];
    float a0 = 0.f, a1 = 0.f, a2 = 0.f, a3 = 0.f;
    float a4 = 0.f, a5 = 0.f, a6 = 0.f, a7 = 0.f;
    int e = start + slot;
    for (; e + 8 < end; e += 16) {
        int s1 = csr_src[e];
        int s2 = csr_src[e + 8];
        uint4 v1 = *(const uint4*)(h1b + ((size_t)s1 << 4) + (hf << 3));
        uint4 v2 = *(const uint4*)(h1b + ((size_t)s2 << 4) + (hf << 3));
        a0 += __uint_as_float(v1.x << 16); a1 += __uint_as_float(v1.x & 0xFFFF0000u);
        a2 += __uint_as_float(v1.y << 16); a3 += __uint_as_float(v1.y & 0xFFFF0000u);
        a4 += __uint_as_float(v1.z << 16); a5 += __uint_as_float(v1.z & 0xFFFF0000u);
        a6 += __uint_as_float(v1.w << 16); a7 += __uint_as_float(v1.w & 0xFFFF0000u);
        a0 += __uint_as_float(v2.x << 16); a1 += __uint_as_float(v2.x & 0xFFFF0000u);
        a2 += __uint_as_float(v2.y << 16); a3 += __uint_as_float(v2.y & 0xFFFF0000u);
        a4 += __uint_as_float(v2.z << 16); a5 += __uint_as_float(v2.z & 0xFFFF0000u);
        a6 += __uint_as_float(v2.w << 16); a7 += __uint_as_float(v2.w & 0xFFFF0000u);
    }
    for (; e < end; e += 8) {
        int s1 = csr_src[e];
        uint4 v1 = *(const uint4*)(h1b + ((size_t)s1 << 4) + (hf << 3));
        a0 += __uint_as_float(v1.x << 16); a1 += __uint_as_float(v1.x & 0xFFFF0000u);
        a2 += __uint_as_float(v1.y << 16); a3 += __uint_as_float(v1.y & 0xFFFF0000u);
        a4 += __uint_as_float(v1.z << 16); a5 += __uint_as_float(v1.z & 0xFFFF0000u);
        a6 += __uint_as_float(v1.w << 16); a7 += __uint_as_float(v1.w & 0xFFFF0000u);
    }
#pragma unroll
    for (int m = 2; m <= 8; m <<= 1) {
        a0 += __shfl_xor(a0, m, 16);
        a1 += __shfl_xor(a1, m, 16);
        a2 += __shfl_xor(a2, m, 16);
        a3 += __shfl_xor(a3, m, 16);
        a4 += __shfl_xor(a4, m, 16);
        a5 += __shfl_xor(a5, m, 16);
        a6 += __shfl_xor(a6, m, 16);
        a7 += __shfl_xor(a7, m, 16);
    }
    if (slot == 0) {
        uint4 sv = *(const uint4*)(h1b + ((size_t)i << 4) + (hf << 3));
        float s0 = __uint_as_float(sv.x << 16), s1 = __uint_as_float(sv.x & 0xFFFF0000u);
        float s2 = __uint_as_float(sv.y << 16), s3 = __uint_as_float(sv.y & 0xFFFF0000u);
        float s4 = __uint_as_float(sv.z << 16), s5 = __uint_as_float(sv.z & 0xFFFF0000u);
        float s6 = __uint_as_float(sv.w << 16), s7 = __uint_as_float(sv.w & 0xFFFF0000u);
        int f0 = hf * 8;
        float r0 = fmaxf(di * (a0 + s0) + b1[f0 + 0], 0.f);
        float r1 = fmaxf(di * (a1 + s1) + b1[f0 + 1], 0.f);
        float r2 = fmaxf(di * (a2 + s2) + b1[f0 + 2], 0.f);
        float r3 = fmaxf(di * (a3 + s3) + b1[f0 + 3], 0.f);
        float r4 = fmaxf(di * (a4 + s4) + b1[f0 + 4], 0.f);
        float r5 = fmaxf(di * (a5 + s5) + b1[f0 + 5], 0.f);
        float r6 = fmaxf(di * (a6 + s6) + b1[f0 + 6], 0.f);
        float r7 = fmaxf(di * (a7 + s7) + b1[f0 + 7], 0.f);
        float p0 = r0 * W2[(f0 + 0) * 2] + r1 * W2[(f0 + 1) * 2] +
                   r2 * W2[(f0 + 2) * 2] + r3 * W2[(f0 + 3) * 2] +
                   r4 * W2[(f0 + 4) * 2] + r5 * W2[(f0 + 5) * 2] +
                   r6 * W2[(f0 + 6) * 2] + r7 * W2[(f0 + 7) * 2];
        float p1 = r0 * W2[(f0 + 0) * 2 + 1] + r1 * W2[(f0 + 1) * 2 + 1] +
                   r2 * W2[(f0 + 2) * 2 + 1] + r3 * W2[(f0 + 3) * 2 + 1] +
                   r4 * W2[(f0 + 4) * 2 + 1] + r5 * W2[(f0 + 5) * 2 + 1] +
                   r6 * W2[(f0 + 6) * 2 + 1] + r7 * W2[(f0 + 7) * 2 + 1];
        p0 += __shfl_xor(p0, 1, 2);
        p1 += __shfl_xor(p1, 1, 2);
        if (hf == 0) {
            float2 hv;
            hv.x = di * p0;
            hv.y = di * p1;
            *(float2*)(h2b + (size_t)i * 2) = hv;
        }
    }
}

// gather2: 4 lanes/node; o = di*(sum h2b[src] + h2b[i]) + b2; log_softmax.
__global__ __launch_bounds__(256) void k_gather2(const int* __restrict__ row_start,
                                                 const int* __restrict__ csr_src,
                                                 const float* __restrict__ dinv,
                                                 const float* __restrict__ h2b,
                                                 const float* __restrict__ b2,
                                                 float* __restrict__ out) {
    int t = threadIdx.x;
    int i = blockIdx.x * 64 + (t >> 2);
    int l = t & 3;
    int start = row_start[i];
    int end = row_start[i + 1];
    float di = dinv[i];
    float o0 = 0.f, o1 = 0.f;
    for (int e = start + l; e < end; e += 4) {
        int src = csr_src[e];
        float2 hv = *(const float2*)(h2b + (size_t)src * 2);
        o0 += hv.x;
        o1 += hv.y;
    }
    o0 += __shfl_xor(o0, 1, 4);
    o1 += __shfl_xor(o1, 1, 4);
    o0 += __shfl_xor(o0, 2, 4);
    o1 += __shfl_xor(o1, 2, 4);
    if (l == 0) {
        float2 hs = *(const float2*)(h2b + (size_t)i * 2);
        float f0 = di * (o0 + hs.x) + b2[0];
        float f1 = di * (o1 + hs.y) + b2[1];
        float m = fmaxf(f0, f1);
        float lse = m + logf(expf(f0 - m) + expf(f1 - m));
        out[(size_t)i * 2 + 0] = f0 - lse;
        out[(size_t)i * 2 + 1] = f1 - lse;
    }
}

extern "C" void kernel_launch(void* const* d_in, const int* in_sizes, int n_in,
                              void* d_out, int out_size, void* d_ws, size_t ws_size,
                              hipStream_t stream) {
    const float* x  = (const float*)d_in[0];
    const void*  ei = d_in[1];
    const float* W1 = (const float*)d_in[2];
    const float* b1 = (const float*)d_in[3];
    const float* W2 = (const float*)d_in[4];
    const float* b2 = (const float*)d_in[5];

    int*            wsw       = (int*)d_ws;
    float*          dinv      = (float*)(wsw + OFF_DINV);
    int*            row_start = wsw + OFF_ROW;
    int*            bcount    = wsw + OFF_BCOUNT;
    int*            bbase     = wsw + OFF_BBASE;
    int*            histB     = wsw + OFF_HISTB;
    int*            baseB     = wsw + OFF_BASEB;
    unsigned*       ebuf      = (unsigned*)(wsw + OFF_EBUF);   // becomes csr_src
    unsigned short* h1b       = (unsigned short*)(wsw + OFF_H1B);
    float*          h2b       = (float*)(wsw + OFF_H2B);
    float*          out       = (float*)d_out;

    k_init<<<1, 512, 0, stream>>>(bcount);
    k_bhist<<<NCHUNK, 512, 0, stream>>>(ei, bcount, histB);
    k_bscan<<<1, 512, 0, stream>>>(bcount, bbase, row_start);
    k_colscan<<<512, 256, 0, stream>>>(histB, bbase, baseB);
    k_bscatter<<<NCHUNK, 512, 0, stream>>>(ei, histB, baseB, ebuf);
    k_bsort<<<NB, 512, 0, stream>>>(ebuf, bbase, row_start, dinv);
    k_gemm1<<<(N_NODES + 63) / 64, 256, 0, stream>>>(x, W1, dinv, h1b);
    k_gather1<<<N_NODES / 16, 256, 0, stream>>>(row_start, (const int*)ebuf, dinv, h1b, b1, W2, h2b);
    k_gather2<<<N_NODES / 64, 256, 0, stream>>>(row_start, (const int*)ebuf, dinv, h2b, b2, out);
}

// Round 14
// 240.670 us; speedup vs baseline: 3.5778x; 1.0283x over previous
//
#include <hip/hip_runtime.h>
#include <math.h>

#define N_NODES 200000
#define N_EDGES 6400000
#define F_IN 128
#define NH 16
#define BKT_NODES 512   // nodes per bucket
#define NB 391          // bsort blocks = ceil(200000/512)
#define CH 8192         // edges per chunk
#define NCHUNK 782      // ceil(6400000/8192)
#define BKT_CAP 17408   // LDS stage cap per bucket (mean 16384, +8 sigma)

// ws layout in 4-byte words. ebuf (packed edges) is reused in-place as csr_src.
#define OFF_DINV    0            // [N] float
#define OFF_ROW     200000       // [N+1] int
#define OFF_BCOUNT  400004       // [512] int
#define OFF_BBASE   400516       // [512] int
#define OFF_HISTB   401028       // [NCHUNK*512] int  per-block bucket histograms
#define OFF_BASEB   801412       // [NCHUNK*512] int  per-block global bucket bases
#define OFF_EBUF    1201796      // [E] u32 packed (dst_local<<18)|src ; later csr_src
#define OFF_H1B     7601796      // [8N words] bf16 h1b[N][16] (= dinv*h1)
#define OFF_H2B     9201796      // [2N] float h2b (= dinv*h2)

__device__ __forceinline__ unsigned bf16rne(float f) {
    unsigned u = __float_as_uint(f);
    unsigned r = ((u >> 16) & 1u) + 0x7FFFu;
    return (u + r) >> 16;
}

// Wave-uniform int64-vs-int32 detection: read first 64 qwords; if edges are
// int32 pairs, reinterpreted i64 values land outside [0, N_NODES) w.h.p.
__device__ __forceinline__ int detect_is32(const void* edges) {
    const long long* e64 = (const long long*)edges;
    long long v = e64[threadIdx.x & 63];
    return __any((v < 0) || (v >= N_NODES)) ? 1 : 0;
}

__global__ __launch_bounds__(512) void k_init(int* bcount) {
    bcount[threadIdx.x] = 0;
}

// per-chunk 512-bin histogram; persists per-block hist AND accumulates global.
__global__ __launch_bounds__(512) void k_bhist(const void* edges, int* bcount,
                                               int* __restrict__ histB) {
    __shared__ int sH[512];
    int t = threadIdx.x;
    int is32 = detect_is32(edges);
    sH[t] = 0;
    __syncthreads();
    long long e0 = (long long)blockIdx.x * CH;
    int nloc = (int)min((long long)CH, (long long)N_EDGES - e0);
    int n4 = nloc >> 2;
    if (is32) {
        const int4* d4 = (const int4*)((const int*)edges + N_EDGES + e0);
        for (int j = t; j < n4; j += 512) {
            int4 d = d4[j];
            atomicAdd(&sH[d.x >> 9], 1);
            atomicAdd(&sH[d.y >> 9], 1);
            atomicAdd(&sH[d.z >> 9], 1);
            atomicAdd(&sH[d.w >> 9], 1);
        }
    } else {
        const longlong2* d2 = (const longlong2*)((const long long*)edges + N_EDGES + e0);
        for (int j = t; j < n4; j += 512) {
            longlong2 a = d2[2 * j], b = d2[2 * j + 1];
            atomicAdd(&sH[(int)a.x >> 9], 1);
            atomicAdd(&sH[(int)a.y >> 9], 1);
            atomicAdd(&sH[(int)b.x >> 9], 1);
            atomicAdd(&sH[(int)b.y >> 9], 1);
        }
    }
    __syncthreads();
    histB[blockIdx.x * 512 + t] = sH[t];
    if (sH[t]) atomicAdd(&bcount[t], sH[t]);
}

// single block of 512: exclusive scan bcount -> bbase; row_start[N]=E
__global__ __launch_bounds__(512) void k_bscan(const int* __restrict__ bcount,
                                               int* __restrict__ bbase,
                                               int* __restrict__ row_start) {
    __shared__ int sWsum[8];
    int t = threadIdx.x;
    int c = bcount[t];
    int lane = t & 63, w = t >> 6;
    int v = c;
    for (int off = 1; off < 64; off <<= 1) {
        int nbr = __shfl_up(v, off, 64);
        if (lane >= off) v += nbr;
    }
    if (lane == 63) sWsum[w] = v;
    __syncthreads();
    int add = 0;
    for (int k = 0; k < w; k++) add += sWsum[k];
    int excl = v + add - c;
    bbase[t] = excl;
    if (t == 0) row_start[N_NODES] = N_EDGES;
}

// one block per bucket q: prefix-scan histB[blk][q] over blk -> per-block
// global write base baseB[blk][q] = bbase[q] + sum_{b'<blk} histB[b'][q]
__global__ __launch_bounds__(256) void k_colscan(const int* __restrict__ histB,
                                                 const int* __restrict__ bbase,
                                                 int* __restrict__ baseB) {
    __shared__ int sW[4];
    __shared__ int sCarry;
    int q = blockIdx.x;
    int t = threadIdx.x;
    int lane = t & 63, w = t >> 6;
    if (t == 0) sCarry = bbase[q];
    __syncthreads();
    for (int c0 = 0; c0 < NCHUNK; c0 += 256) {
        int blk = c0 + t;
        int orig = (blk < NCHUNK) ? histB[blk * 512 + q] : 0;
        int v = orig;
        for (int off = 1; off < 64; off <<= 1) {
            int nbr = __shfl_up(v, off, 64);
            if (lane >= off) v += nbr;
        }
        if (lane == 63) sW[w] = v;
        __syncthreads();
        int add = sCarry;
        for (int k = 0; k < w; k++) add += sW[k];
        if (blk < NCHUNK) baseB[blk * 512 + q] = add + v - orig;
        __syncthreads();
        if (t == 255) sCarry = add + v;
        __syncthreads();
    }
}

// single edge read; local starts from histB; LDS rank-scatter; coalesced
// copy-out via baseB.
__global__ __launch_bounds__(512) void k_bscatter(const void* edges,
                                                  const int* __restrict__ histB,
                                                  const int* __restrict__ baseB,
                                                  unsigned* __restrict__ ebuf) {
    __shared__ unsigned sS[CH];    // 32 KB sorted packed edges
    __shared__ int sStart[512];    // local exclusive starts
    __shared__ int sCur[512];      // rank cursors
    __shared__ int sGb[512];       // baseB[q] - sStart[q]  (copy-out fold)
    __shared__ int sWsum[8];
    int t = threadIdx.x;
    int is32 = detect_is32(edges);
    long long e0 = (long long)blockIdx.x * CH;
    int nloc = (int)min((long long)CH, (long long)N_EDGES - e0);
    int n4 = nloc >> 2;
    int h = histB[blockIdx.x * 512 + t];
    int g = baseB[blockIdx.x * 512 + t];
    int lane = t & 63, w = t >> 6;
    int v = h;
    for (int off = 1; off < 64; off <<= 1) {
        int nbr = __shfl_up(v, off, 64);
        if (lane >= off) v += nbr;
    }
    if (lane == 63) sWsum[w] = v;
    __syncthreads();
    int add = 0;
    for (int k = 0; k < w; k++) add += sWsum[k];
    int excl = v + add - h;
    sStart[t] = excl;
    sCur[t] = excl;
    sGb[t] = g - excl;
    __syncthreads();
    // single edge pass: rank-scatter into LDS (sorted by bucket)
    if (is32) {
        const int4* s4 = (const int4*)((const int*)edges + e0);
        const int4* d4 = (const int4*)((const int*)edges + N_EDGES + e0);
        for (int j = t; j < n4; j += 512) {
            int4 s = s4[j];
            int4 d = d4[j];
            int r;
            r = atomicAdd(&sCur[d.x >> 9], 1); sS[r] = (unsigned)(((d.x & 511) << 18) | s.x);
            r = atomicAdd(&sCur[d.y >> 9], 1); sS[r] = (unsigned)(((d.y & 511) << 18) | s.y);
            r = atomicAdd(&sCur[d.z >> 9], 1); sS[r] = (unsigned)(((d.z & 511) << 18) | s.z);
            r = atomicAdd(&sCur[d.w >> 9], 1); sS[r] = (unsigned)(((d.w & 511) << 18) | s.w);
        }
    } else {
        const longlong2* s2 = (const longlong2*)((const long long*)edges + e0);
        const longlong2* d2 = (const longlong2*)((const long long*)edges + N_EDGES + e0);
        for (int j = t; j < n4; j += 512) {
            longlong2 sa = s2[2 * j], sb = s2[2 * j + 1];
            longlong2 da = d2[2 * j], db = d2[2 * j + 1];
            int s0 = (int)sa.x, s1 = (int)sa.y, s2i = (int)sb.x, s3 = (int)sb.y;
            int d0 = (int)da.x, d1 = (int)da.y, d2i = (int)db.x, d3 = (int)db.y;
            int r;
            r = atomicAdd(&sCur[d0 >> 9], 1); sS[r] = (unsigned)(((d0 & 511) << 18) | s0);
            r = atomicAdd(&sCur[d1 >> 9], 1); sS[r] = (unsigned)(((d1 & 511) << 18) | s1);
            r = atomicAdd(&sCur[d2i >> 9], 1); sS[r] = (unsigned)(((d2i & 511) << 18) | s2i);
            r = atomicAdd(&sCur[d3 >> 9], 1); sS[r] = (unsigned)(((d3 & 511) << 18) | s3);
        }
    }
    __syncthreads();
    // coalesced copy-out; rightmost bucket with sStart <= j via binary search
    for (int j = t; j < nloc; j += 512) {
        int lo = 0;
#pragma unroll
        for (int step = 256; step > 0; step >>= 1) {
            int mid = lo + step;
            if (mid < 512 && sStart[mid] <= j) lo = mid;
        }
        ebuf[sGb[lo] + j] = sS[j];
    }
}

// one block per 512-node bucket, 1024 threads (71.7 KB LDS -> 2 blocks/CU,
// 32 waves/CU vs 16 at 512 thr): stage, 512-bin count+scan -> row_start/dinv,
// ranked scatter writes csr_src IN PLACE over ebuf.
__global__ __launch_bounds__(1024) void k_bsort(unsigned* ebuf,
                                                const int* __restrict__ bbase,
                                                int* __restrict__ row_start,
                                                float* __restrict__ dinv) {
    __shared__ unsigned sE[BKT_CAP];
    __shared__ int sH[512];
    __shared__ int sWsum[8];
    int b = blockIdx.x, t = threadIdx.x;
    int base = bbase[b];
    int cnt = bbase[b + 1] - base;
    int cap = cnt < BKT_CAP ? cnt : BKT_CAP;
    for (int j = t; j < cap; j += 1024) sE[j] = ebuf[base + j];
    if (t < 512) sH[t] = 0;
    __syncthreads();
    for (int j = t; j < cnt; j += 1024) {
        unsigned p = (j < cap) ? sE[j] : ebuf[base + j];
        atomicAdd(&sH[p >> 18], 1);
    }
    __syncthreads();
    int lane = t & 63, w = t >> 6;
    int h = (t < 512) ? sH[t] : 0;
    int v = h;
    for (int off = 1; off < 64; off <<= 1) {
        int nbr = __shfl_up(v, off, 64);
        if (lane >= off) v += nbr;
    }
    if (t < 512 && lane == 63) sWsum[w] = v;
    __syncthreads();
    if (t < 512) {
        int add = 0;
        for (int k = 0; k < w; k++) add += sWsum[k];
        int excl = v + add - h;
        int node = b * BKT_NODES + t;
        if (node < N_NODES) {
            row_start[node] = base + excl;
            dinv[node] = rsqrtf((float)h + 1.0f);
        }
        sH[t] = excl;   // safe: hist reads completed at previous barrier
    }
    __syncthreads();
    for (int j = t; j < cnt; j += 1024) {
        unsigned p = (j < cap) ? sE[j] : ebuf[base + j];
        int pos = atomicAdd(&sH[p >> 18], 1);
        ebuf[base + pos] = p & 0x3FFFF;
    }
}

// h1b = dinv * (x @ W1), bf16 [N][16]. 4 lanes per row, k-phased: each 4-lane
// group issues contiguous 64 B per step -> every byte of x fetched exactly once.
__global__ __launch_bounds__(256) void k_gemm1(const float* __restrict__ x,
                                               const float* __restrict__ W1,
                                               const float* __restrict__ dinv,
                                               unsigned short* __restrict__ h1b) {
    __shared__ float sWt[NH * F_IN];   // [c][k]
    int t = threadIdx.x;
    for (int q = t; q < 512; q += 256) {
        float4 wv = ((const float4*)W1)[q];
        int k = q >> 2, c0 = (q & 3) * 4;
        sWt[(c0 + 0) * F_IN + k] = wv.x;
        sWt[(c0 + 1) * F_IN + k] = wv.y;
        sWt[(c0 + 2) * F_IN + k] = wv.z;
        sWt[(c0 + 3) * F_IN + k] = wv.w;
    }
    __syncthreads();
    int r = blockIdx.x * 64 + (t >> 2);
    int l = t & 3;
    if (r >= N_NODES) return;
    float acc[NH];
#pragma unroll
    for (int c = 0; c < NH; c++) acc[c] = 0.f;
    const float4* xr = (const float4*)(x + (size_t)r * F_IN);
#pragma unroll
    for (int s = 0; s < 8; s++) {
        float4 xv = xr[s * 4 + l];          // row bytes [s*64 + l*16, +16)
        int k0 = s * 16 + l * 4;
#pragma unroll
        for (int c = 0; c < NH; c++) {
            float4 wv = *(const float4*)&sWt[c * F_IN + k0];
            acc[c] += xv.x * wv.x + xv.y * wv.y + xv.z * wv.z + xv.w * wv.w;
        }
    }
#pragma unroll
    for (int c = 0; c < NH; c++) {
        acc[c] += __shfl_xor(acc[c], 1, 4);
        acc[c] += __shfl_xor(acc[c], 2, 4);
    }
    float di = dinv[r];
    unsigned p0 = bf16rne(acc[l * 4 + 0] * di) | (bf16rne(acc[l * 4 + 1] * di) << 16);
    unsigned p1 = bf16rne(acc[l * 4 + 2] * di) | (bf16rne(acc[l * 4 + 3] * di) << 16);
    *(uint2*)(h1b + (size_t)r * NH + l * 4) = make_uint2(p0, p1);
}

// gather1: 16 lanes/node = 8 edge-slots x 2 feature-halves; uint4 (16 B) per
// lane = one 32 B request per edge; 2x unrolled for MLP (R11-validated).
__global__ __launch_bounds__(256) void k_gather1(const int* __restrict__ row_start,
                                                 const int* __restrict__ csr_src,
                                                 const float* __restrict__ dinv,
                                                 const unsigned short* __restrict__ h1b,
                                                 const float* __restrict__ b1,
                                                 const float* __restrict__ W2,
                                                 float* __restrict__ h2b) {
    int t = threadIdx.x;
    int i = blockIdx.x * 16 + (t >> 4);
    int hf = t & 1;           // feature half: feats 0-7 or 8-15
    int slot = (t >> 1) & 7;  // 8 edge slots
    int start = row_start[i];
    int end = row_start[i + 1];
    float di = dinv[i];
    float a0 = 0.f, a1 = 0.f, a2 = 0.f, a3 = 0.f;
    float a4 = 0.f, a5 = 0.f, a6 = 0.f, a7 = 0.f;
    int e = start + slot;
    for (; e + 8 < end; e += 16) {
        int s1 = csr_src[e];
        int s2 = csr_src[e + 8];
        uint4 v1 = *(const uint4*)(h1b + ((size_t)s1 << 4) + (hf << 3));
        uint4 v2 = *(const uint4*)(h1b + ((size_t)s2 << 4) + (hf << 3));
        a0 += __uint_as_float(v1.x << 16); a1 += __uint_as_float(v1.x & 0xFFFF0000u);
        a2 += __uint_as_float(v1.y << 16); a3 += __uint_as_float(v1.y & 0xFFFF0000u);
        a4 += __uint_as_float(v1.z << 16); a5 += __uint_as_float(v1.z & 0xFFFF0000u);
        a6 += __uint_as_float(v1.w << 16); a7 += __uint_as_float(v1.w & 0xFFFF0000u);
        a0 += __uint_as_float(v2.x << 16); a1 += __uint_as_float(v2.x & 0xFFFF0000u);
        a2 += __uint_as_float(v2.y << 16); a3 += __uint_as_float(v2.y & 0xFFFF0000u);
        a4 += __uint_as_float(v2.z << 16); a5 += __uint_as_float(v2.z & 0xFFFF0000u);
        a6 += __uint_as_float(v2.w << 16); a7 += __uint_as_float(v2.w & 0xFFFF0000u);
    }
    for (; e < end; e += 8) {
        int s1 = csr_src[e];
        uint4 v1 = *(const uint4*)(h1b + ((size_t)s1 << 4) + (hf << 3));
        a0 += __uint_as_float(v1.x << 16); a1 += __uint_as_float(v1.x & 0xFFFF0000u);
        a2 += __uint_as_float(v1.y << 16); a3 += __uint_as_float(v1.y & 0xFFFF0000u);
        a4 += __uint_as_float(v1.z << 16); a5 += __uint_as_float(v1.z & 0xFFFF0000u);
        a6 += __uint_as_float(v1.w << 16); a7 += __uint_as_float(v1.w & 0xFFFF0000u);
    }
#pragma unroll
    for (int m = 2; m <= 8; m <<= 1) {
        a0 += __shfl_xor(a0, m, 16);
        a1 += __shfl_xor(a1, m, 16);
        a2 += __shfl_xor(a2, m, 16);
        a3 += __shfl_xor(a3, m, 16);
        a4 += __shfl_xor(a4, m, 16);
        a5 += __shfl_xor(a5, m, 16);
        a6 += __shfl_xor(a6, m, 16);
        a7 += __shfl_xor(a7, m, 16);
    }
    if (slot == 0) {
        uint4 sv = *(const uint4*)(h1b + ((size_t)i << 4) + (hf << 3));
        float s0 = __uint_as_float(sv.x << 16), s1 = __uint_as_float(sv.x & 0xFFFF0000u);
        float s2 = __uint_as_float(sv.y << 16), s3 = __uint_as_float(sv.y & 0xFFFF0000u);
        float s4 = __uint_as_float(sv.z << 16), s5 = __uint_as_float(sv.z & 0xFFFF0000u);
        float s6 = __uint_as_float(sv.w << 16), s7 = __uint_as_float(sv.w & 0xFFFF0000u);
        int f0 = hf * 8;
        float r0 = fmaxf(di * (a0 + s0) + b1[f0 + 0], 0.f);
        float r1 = fmaxf(di * (a1 + s1) + b1[f0 + 1], 0.f);
        float r2 = fmaxf(di * (a2 + s2) + b1[f0 + 2], 0.f);
        float r3 = fmaxf(di * (a3 + s3) + b1[f0 + 3], 0.f);
        float r4 = fmaxf(di * (a4 + s4) + b1[f0 + 4], 0.f);
        float r5 = fmaxf(di * (a5 + s5) + b1[f0 + 5], 0.f);
        float r6 = fmaxf(di * (a6 + s6) + b1[f0 + 6], 0.f);
        float r7 = fmaxf(di * (a7 + s7) + b1[f0 + 7], 0.f);
        float p0 = r0 * W2[(f0 + 0) * 2] + r1 * W2[(f0 + 1) * 2] +
                   r2 * W2[(f0 + 2) * 2] + r3 * W2[(f0 + 3) * 2] +
                   r4 * W2[(f0 + 4) * 2] + r5 * W2[(f0 + 5) * 2] +
                   r6 * W2[(f0 + 6) * 2] + r7 * W2[(f0 + 7) * 2];
        float p1 = r0 * W2[(f0 + 0) * 2 + 1] + r1 * W2[(f0 + 1) * 2 + 1] +
                   r2 * W2[(f0 + 2) * 2 + 1] + r3 * W2[(f0 + 3) * 2 + 1] +
                   r4 * W2[(f0 + 4) * 2 + 1] + r5 * W2[(f0 + 5) * 2 + 1] +
                   r6 * W2[(f0 + 6) * 2 + 1] + r7 * W2[(f0 + 7) * 2 + 1];
        p0 += __shfl_xor(p0, 1, 2);
        p1 += __shfl_xor(p1, 1, 2);
        if (hf == 0) {
            float2 hv;
            hv.x = di * p0;
            hv.y = di * p1;
            *(float2*)(h2b + (size_t)i * 2) = hv;
        }
    }
}

// gather2: 4 lanes/node, 2x unrolled MLP; o = di*(sum h2b[src] + h2b[i]) + b2;
// log_softmax.
__global__ __launch_bounds__(256) void k_gather2(const int* __restrict__ row_start,
                                                 const int* __restrict__ csr_src,
                                                 const float* __restrict__ dinv,
                                                 const float* __restrict__ h2b,
                                                 const float* __restrict__ b2,
                                                 float* __restrict__ out) {
    int t = threadIdx.x;
    int i = blockIdx.x * 64 + (t >> 2);
    int l = t & 3;
    int start = row_start[i];
    int end = row_start[i + 1];
    float di = dinv[i];
    float o0 = 0.f, o1 = 0.f;
    int e = start + l;
    for (; e + 4 < end; e += 8) {
        int s1 = csr_src[e];
        int s2 = csr_src[e + 4];
        float2 hv1 = *(const float2*)(h2b + (size_t)s1 * 2);
        float2 hv2 = *(const float2*)(h2b + (size_t)s2 * 2);
        o0 += hv1.x + hv2.x;
        o1 += hv1.y + hv2.y;
    }
    for (; e < end; e += 4) {
        int src = csr_src[e];
        float2 hv = *(const float2*)(h2b + (size_t)src * 2);
        o0 += hv.x;
        o1 += hv.y;
    }
    o0 += __shfl_xor(o0, 1, 4);
    o1 += __shfl_xor(o1, 1, 4);
    o0 += __shfl_xor(o0, 2, 4);
    o1 += __shfl_xor(o1, 2, 4);
    if (l == 0) {
        float2 hs = *(const float2*)(h2b + (size_t)i * 2);
        float f0 = di * (o0 + hs.x) + b2[0];
        float f1 = di * (o1 + hs.y) + b2[1];
        float m = fmaxf(f0, f1);
        float lse = m + logf(expf(f0 - m) + expf(f1 - m));
        out[(size_t)i * 2 + 0] = f0 - lse;
        out[(size_t)i * 2 + 1] = f1 - lse;
    }
}

extern "C" void kernel_launch(void* const* d_in, const int* in_sizes, int n_in,
                              void* d_out, int out_size, void* d_ws, size_t ws_size,
                              hipStream_t stream) {
    const float* x  = (const float*)d_in[0];
    const void*  ei = d_in[1];
    const float* W1 = (const float*)d_in[2];
    const float* b1 = (const float*)d_in[3];
    const float* W2 = (const float*)d_in[4];
    const float* b2 = (const float*)d_in[5];

    int*            wsw       = (int*)d_ws;
    float*          dinv      = (float*)(wsw + OFF_DINV);
    int*            row_start = wsw + OFF_ROW;
    int*            bcount    = wsw + OFF_BCOUNT;
    int*            bbase     = wsw + OFF_BBASE;
    int*            histB     = wsw + OFF_HISTB;
    int*            baseB     = wsw + OFF_BASEB;
    unsigned*       ebuf      = (unsigned*)(wsw + OFF_EBUF);   // becomes csr_src
    unsigned short* h1b       = (unsigned short*)(wsw + OFF_H1B);
    float*          h2b       = (float*)(wsw + OFF_H2B);
    float*          out       = (float*)d_out;

    k_init<<<1, 512, 0, stream>>>(bcount);
    k_bhist<<<NCHUNK, 512, 0, stream>>>(ei, bcount, histB);
    k_bscan<<<1, 512, 0, stream>>>(bcount, bbase, row_start);
    k_colscan<<<512, 256, 0, stream>>>(histB, bbase, baseB);
    k_bscatter<<<NCHUNK, 512, 0, stream>>>(ei, histB, baseB, ebuf);
    k_bsort<<<NB, 1024, 0, stream>>>(ebuf, bbase, row_start, dinv);
    k_gemm1<<<(N_NODES + 63) / 64, 256, 0, stream>>>(x, W1, dinv, h1b);
    k_gather1<<<N_NODES / 16, 256, 0, stream>>>(row_start, (const int*)ebuf, dinv, h1b, b1, W2, h2b);
    k_gather2<<<N_NODES / 64, 256, 0, stream>>>(row_start, (const int*)ebuf, dinv, h2b, b2, out);
}

// Round 15
// 232.653 us; speedup vs baseline: 3.7011x; 1.0345x over previous
//
#include <hip/hip_runtime.h>
#include <math.h>

#define N_NODES 200000
#define N_EDGES 6400000
#define F_IN 128
#define NH 16
#define BKT_NODES 512   // nodes per bucket
#define NB 391          // bsort blocks = ceil(200000/512)
#define CH 16384        // edges per chunk
#define NCHUNK 391      // ceil(6400000/16384)
#define BKT_CAP 17408   // LDS stage cap per bucket (mean 16384, +8 sigma)

// ws layout in 4-byte words. ebuf (packed edges) is reused in-place as csr_src.
#define OFF_DINV    0            // [N] float
#define OFF_ROW     200000       // [N+1] int
#define OFF_BCOUNT  400004       // [512] int
#define OFF_BBASE   400516       // [512] int
#define OFF_HISTB   401028       // [NCHUNK*512] int
#define OFF_BASEB   601220       // [NCHUNK*512] int
#define OFF_EBUF    801412       // [E] u32 packed (dst_local<<18)|src ; later csr_src
#define OFF_H1B     7201412      // [8N words] bf16 h1b[N][16] (= dinv*h1); 16B-aligned
#define OFF_H2B     8801412      // [2N] float h2b (= dinv*h2)

__device__ __forceinline__ unsigned bf16rne(float f) {
    unsigned u = __float_as_uint(f);
    unsigned r = ((u >> 16) & 1u) + 0x7FFFu;
    return (u + r) >> 16;
}

// Wave-uniform int64-vs-int32 detection: read first 64 qwords; if edges are
// int32 pairs, reinterpreted i64 values land outside [0, N_NODES) w.h.p.
__device__ __forceinline__ int detect_is32(const void* edges) {
    const long long* e64 = (const long long*)edges;
    long long v = e64[threadIdx.x & 63];
    return __any((v < 0) || (v >= N_NODES)) ? 1 : 0;
}

__global__ __launch_bounds__(512) void k_init(int* bcount) {
    bcount[threadIdx.x] = 0;
}

// per-chunk 512-bin histogram; persists per-block hist AND accumulates global.
__global__ __launch_bounds__(1024) void k_bhist(const void* edges, int* bcount,
                                                int* __restrict__ histB) {
    __shared__ int sH[512];
    int t = threadIdx.x;
    int is32 = detect_is32(edges);
    if (t < 512) sH[t] = 0;
    __syncthreads();
    long long e0 = (long long)blockIdx.x * CH;
    int nloc = (int)min((long long)CH, (long long)N_EDGES - e0);
    int n4 = nloc >> 2;
    if (is32) {
        const int4* d4 = (const int4*)((const int*)edges + N_EDGES + e0);
        for (int j = t; j < n4; j += 1024) {
            int4 d = d4[j];
            atomicAdd(&sH[d.x >> 9], 1);
            atomicAdd(&sH[d.y >> 9], 1);
            atomicAdd(&sH[d.z >> 9], 1);
            atomicAdd(&sH[d.w >> 9], 1);
        }
    } else {
        const longlong2* d2 = (const longlong2*)((const long long*)edges + N_EDGES + e0);
        for (int j = t; j < n4; j += 1024) {
            longlong2 a = d2[2 * j], b = d2[2 * j + 1];
            atomicAdd(&sH[(int)a.x >> 9], 1);
            atomicAdd(&sH[(int)a.y >> 9], 1);
            atomicAdd(&sH[(int)b.x >> 9], 1);
            atomicAdd(&sH[(int)b.y >> 9], 1);
        }
    }
    __syncthreads();
    if (t < 512) {
        histB[blockIdx.x * 512 + t] = sH[t];
        if (sH[t]) atomicAdd(&bcount[t], sH[t]);
    }
}

// single block of 512: exclusive scan bcount -> bbase; row_start[N]=E
__global__ __launch_bounds__(512) void k_bscan(const int* __restrict__ bcount,
                                               int* __restrict__ bbase,
                                               int* __restrict__ row_start) {
    __shared__ int sWsum[8];
    int t = threadIdx.x;
    int c = bcount[t];
    int lane = t & 63, w = t >> 6;
    int v = c;
    for (int off = 1; off < 64; off <<= 1) {
        int nbr = __shfl_up(v, off, 64);
        if (lane >= off) v += nbr;
    }
    if (lane == 63) sWsum[w] = v;
    __syncthreads();
    int add = 0;
    for (int k = 0; k < w; k++) add += sWsum[k];
    int excl = v + add - c;
    bbase[t] = excl;
    if (t == 0) row_start[N_NODES] = N_EDGES;
}

// one block per bucket q: prefix-scan histB[blk][q] over blk -> per-block
// global write base baseB[blk][q] = bbase[q] + sum_{b'<blk} histB[b'][q]
__global__ __launch_bounds__(256) void k_colscan(const int* __restrict__ histB,
                                                 const int* __restrict__ bbase,
                                                 int* __restrict__ baseB) {
    __shared__ int sW[4];
    __shared__ int sCarry;
    int q = blockIdx.x;
    int t = threadIdx.x;
    int lane = t & 63, w = t >> 6;
    if (t == 0) sCarry = bbase[q];
    __syncthreads();
    for (int c0 = 0; c0 < NCHUNK; c0 += 256) {
        int blk = c0 + t;
        int orig = (blk < NCHUNK) ? histB[blk * 512 + q] : 0;
        int v = orig;
        for (int off = 1; off < 64; off <<= 1) {
            int nbr = __shfl_up(v, off, 64);
            if (lane >= off) v += nbr;
        }
        if (lane == 63) sW[w] = v;
        __syncthreads();
        int add = sCarry;
        for (int k = 0; k < w; k++) add += sW[k];
        if (blk < NCHUNK) baseB[blk * 512 + q] = add + v - orig;
        __syncthreads();
        if (t == 255) sCarry = add + v;
        __syncthreads();
    }
}

// single edge read; local starts from histB; LDS rank-scatter; coalesced
// copy-out via baseB. 1024 threads, 16K-edge chunks (72 KB LDS -> 2 blk/CU,
// 32 waves/CU; copy-out runs avg 128 B).
__global__ __launch_bounds__(1024) void k_bscatter(const void* edges,
                                                   const int* __restrict__ histB,
                                                   const int* __restrict__ baseB,
                                                   unsigned* __restrict__ ebuf) {
    __shared__ unsigned sS[CH];    // 64 KB sorted packed edges
    __shared__ int sStart[512];    // local exclusive starts
    __shared__ int sCur[512];      // rank cursors
    __shared__ int sGb[512];       // baseB[q] - sStart[q]  (copy-out fold)
    __shared__ int sWsum[8];
    int t = threadIdx.x;
    int is32 = detect_is32(edges);
    long long e0 = (long long)blockIdx.x * CH;
    int nloc = (int)min((long long)CH, (long long)N_EDGES - e0);
    int n4 = nloc >> 2;
    int lane = t & 63, w = t >> 6;
    if (t < 512) {
        int h = histB[blockIdx.x * 512 + t];
        int g = baseB[blockIdx.x * 512 + t];
        int v = h;
        for (int off = 1; off < 64; off <<= 1) {
            int nbr = __shfl_up(v, off, 64);
            if (lane >= off) v += nbr;
        }
        if (lane == 63) sWsum[w] = v;
        __syncthreads();
        int add = 0;
        for (int k = 0; k < w; k++) add += sWsum[k];
        int excl = v + add - h;
        sStart[t] = excl;
        sCur[t] = excl;
        sGb[t] = g - excl;
    } else {
        __syncthreads();
    }
    __syncthreads();
    // single edge pass: rank-scatter into LDS (sorted by bucket)
    if (is32) {
        const int4* s4 = (const int4*)((const int*)edges + e0);
        const int4* d4 = (const int4*)((const int*)edges + N_EDGES + e0);
        for (int j = t; j < n4; j += 1024) {
            int4 s = s4[j];
            int4 d = d4[j];
            int r;
            r = atomicAdd(&sCur[d.x >> 9], 1); sS[r] = (unsigned)(((d.x & 511) << 18) | s.x);
            r = atomicAdd(&sCur[d.y >> 9], 1); sS[r] = (unsigned)(((d.y & 511) << 18) | s.y);
            r = atomicAdd(&sCur[d.z >> 9], 1); sS[r] = (unsigned)(((d.z & 511) << 18) | s.z);
            r = atomicAdd(&sCur[d.w >> 9], 1); sS[r] = (unsigned)(((d.w & 511) << 18) | s.w);
        }
    } else {
        const longlong2* s2 = (const longlong2*)((const long long*)edges + e0);
        const longlong2* d2 = (const longlong2*)((const long long*)edges + N_EDGES + e0);
        for (int j = t; j < n4; j += 1024) {
            longlong2 sa = s2[2 * j], sb = s2[2 * j + 1];
            longlong2 da = d2[2 * j], db = d2[2 * j + 1];
            int s0 = (int)sa.x, s1 = (int)sa.y, s2i = (int)sb.x, s3 = (int)sb.y;
            int d0 = (int)da.x, d1 = (int)da.y, d2i = (int)db.x, d3 = (int)db.y;
            int r;
            r = atomicAdd(&sCur[d0 >> 9], 1); sS[r] = (unsigned)(((d0 & 511) << 18) | s0);
            r = atomicAdd(&sCur[d1 >> 9], 1); sS[r] = (unsigned)(((d1 & 511) << 18) | s1);
            r = atomicAdd(&sCur[d2i >> 9], 1); sS[r] = (unsigned)(((d2i & 511) << 18) | s2i);
            r = atomicAdd(&sCur[d3 >> 9], 1); sS[r] = (unsigned)(((d3 & 511) << 18) | s3);
        }
    }
    __syncthreads();
    // coalesced copy-out; rightmost bucket with sStart <= j via binary search
    for (int j = t; j < nloc; j += 1024) {
        int lo = 0;
#pragma unroll
        for (int step = 256; step > 0; step >>= 1) {
            int mid = lo + step;
            if (mid < 512 && sStart[mid] <= j) lo = mid;
        }
        ebuf[sGb[lo] + j] = sS[j];
    }
}

// one block per 512-node bucket, 1024 threads: stage, 512-bin count+scan ->
// row_start/dinv, ranked scatter writes csr_src IN PLACE over ebuf.
__global__ __launch_bounds__(1024) void k_bsort(unsigned* ebuf,
                                                const int* __restrict__ bbase,
                                                int* __restrict__ row_start,
                                                float* __restrict__ dinv) {
    __shared__ unsigned sE[BKT_CAP];
    __shared__ int sH[512];
    __shared__ int sWsum[8];
    int b = blockIdx.x, t = threadIdx.x;
    int base = bbase[b];
    int cnt = bbase[b + 1] - base;
    int cap = cnt < BKT_CAP ? cnt : BKT_CAP;
    for (int j = t; j < cap; j += 1024) sE[j] = ebuf[base + j];
    if (t < 512) sH[t] = 0;
    __syncthreads();
    for (int j = t; j < cnt; j += 1024) {
        unsigned p = (j < cap) ? sE[j] : ebuf[base + j];
        atomicAdd(&sH[p >> 18], 1);
    }
    __syncthreads();
    int lane = t & 63, w = t >> 6;
    int h = (t < 512) ? sH[t] : 0;
    int v = h;
    for (int off = 1; off < 64; off <<= 1) {
        int nbr = __shfl_up(v, off, 64);
        if (lane >= off) v += nbr;
    }
    if (t < 512 && lane == 63) sWsum[w] = v;
    __syncthreads();
    if (t < 512) {
        int add = 0;
        for (int k = 0; k < w; k++) add += sWsum[k];
        int excl = v + add - h;
        int node = b * BKT_NODES + t;
        if (node < N_NODES) {
            row_start[node] = base + excl;
            dinv[node] = rsqrtf((float)h + 1.0f);
        }
        sH[t] = excl;   // safe: hist reads completed at previous barrier
    }
    __syncthreads();
    for (int j = t; j < cnt; j += 1024) {
        unsigned p = (j < cap) ? sE[j] : ebuf[base + j];
        int pos = atomicAdd(&sH[p >> 18], 1);
        ebuf[base + pos] = p & 0x3FFFF;
    }
}

// h1b = dinv * (x @ W1), bf16 [N][16]. 4 lanes per row, k-phased: each 4-lane
// group issues contiguous 64 B per step -> every byte of x fetched exactly once.
__global__ __launch_bounds__(256) void k_gemm1(const float* __restrict__ x,
                                               const float* __restrict__ W1,
                                               const float* __restrict__ dinv,
                                               unsigned short* __restrict__ h1b) {
    __shared__ float sWt[NH * F_IN];   // [c][k]
    int t = threadIdx.x;
    for (int q = t; q < 512; q += 256) {
        float4 wv = ((const float4*)W1)[q];
        int k = q >> 2, c0 = (q & 3) * 4;
        sWt[(c0 + 0) * F_IN + k] = wv.x;
        sWt[(c0 + 1) * F_IN + k] = wv.y;
        sWt[(c0 + 2) * F_IN + k] = wv.z;
        sWt[(c0 + 3) * F_IN + k] = wv.w;
    }
    __syncthreads();
    int r = blockIdx.x * 64 + (t >> 2);
    int l = t & 3;
    if (r >= N_NODES) return;
    float acc[NH];
#pragma unroll
    for (int c = 0; c < NH; c++) acc[c] = 0.f;
    const float4* xr = (const float4*)(x + (size_t)r * F_IN);
#pragma unroll
    for (int s = 0; s < 8; s++) {
        float4 xv = xr[s * 4 + l];          // row bytes [s*64 + l*16, +16)
        int k0 = s * 16 + l * 4;
#pragma unroll
        for (int c = 0; c < NH; c++) {
            float4 wv = *(const float4*)&sWt[c * F_IN + k0];
            acc[c] += xv.x * wv.x + xv.y * wv.y + xv.z * wv.z + xv.w * wv.w;
        }
    }
#pragma unroll
    for (int c = 0; c < NH; c++) {
        acc[c] += __shfl_xor(acc[c], 1, 4);
        acc[c] += __shfl_xor(acc[c], 2, 4);
    }
    float di = dinv[r];
    unsigned p0 = bf16rne(acc[l * 4 + 0] * di) | (bf16rne(acc[l * 4 + 1] * di) << 16);
    unsigned p1 = bf16rne(acc[l * 4 + 2] * di) | (bf16rne(acc[l * 4 + 3] * di) << 16);
    *(uint2*)(h1b + (size_t)r * NH + l * 4) = make_uint2(p0, p1);
}

__device__ __forceinline__ void acc8(float& a0, float& a1, float& a2, float& a3,
                                     float& a4, float& a5, float& a6, float& a7,
                                     uint4 v) {
    a0 += __uint_as_float(v.x << 16); a1 += __uint_as_float(v.x & 0xFFFF0000u);
    a2 += __uint_as_float(v.y << 16); a3 += __uint_as_float(v.y & 0xFFFF0000u);
    a4 += __uint_as_float(v.z << 16); a5 += __uint_as_float(v.z & 0xFFFF0000u);
    a6 += __uint_as_float(v.w << 16); a7 += __uint_as_float(v.w & 0xFFFF0000u);
}

// gather1: 16 lanes/node = 8 edge-slots x 2 feature-halves; uint4 (16 B) per
// lane = one 32 B request per edge; 4x unrolled MLP.
__global__ __launch_bounds__(256) void k_gather1(const int* __restrict__ row_start,
                                                 const int* __restrict__ csr_src,
                                                 const float* __restrict__ dinv,
                                                 const unsigned short* __restrict__ h1b,
                                                 const float* __restrict__ b1,
                                                 const float* __restrict__ W2,
                                                 float* __restrict__ h2b) {
    int t = threadIdx.x;
    int i = blockIdx.x * 16 + (t >> 4);
    int hf = t & 1;           // feature half: feats 0-7 or 8-15
    int slot = (t >> 1) & 7;  // 8 edge slots
    int start = row_start[i];
    int end = row_start[i + 1];
    float di = dinv[i];
    float a0 = 0.f, a1 = 0.f, a2 = 0.f, a3 = 0.f;
    float a4 = 0.f, a5 = 0.f, a6 = 0.f, a7 = 0.f;
    int e = start + slot;
    for (; e + 24 < end; e += 32) {
        int s1 = csr_src[e];
        int s2 = csr_src[e + 8];
        int s3 = csr_src[e + 16];
        int s4 = csr_src[e + 24];
        uint4 v1 = *(const uint4*)(h1b + ((size_t)s1 << 4) + (hf << 3));
        uint4 v2 = *(const uint4*)(h1b + ((size_t)s2 << 4) + (hf << 3));
        uint4 v3 = *(const uint4*)(h1b + ((size_t)s3 << 4) + (hf << 3));
        uint4 v4 = *(const uint4*)(h1b + ((size_t)s4 << 4) + (hf << 3));
        acc8(a0, a1, a2, a3, a4, a5, a6, a7, v1);
        acc8(a0, a1, a2, a3, a4, a5, a6, a7, v2);
        acc8(a0, a1, a2, a3, a4, a5, a6, a7, v3);
        acc8(a0, a1, a2, a3, a4, a5, a6, a7, v4);
    }
    for (; e < end; e += 8) {
        int s1 = csr_src[e];
        uint4 v1 = *(const uint4*)(h1b + ((size_t)s1 << 4) + (hf << 3));
        acc8(a0, a1, a2, a3, a4, a5, a6, a7, v1);
    }
#pragma unroll
    for (int m = 2; m <= 8; m <<= 1) {
        a0 += __shfl_xor(a0, m, 16);
        a1 += __shfl_xor(a1, m, 16);
        a2 += __shfl_xor(a2, m, 16);
        a3 += __shfl_xor(a3, m, 16);
        a4 += __shfl_xor(a4, m, 16);
        a5 += __shfl_xor(a5, m, 16);
        a6 += __shfl_xor(a6, m, 16);
        a7 += __shfl_xor(a7, m, 16);
    }
    if (slot == 0) {
        uint4 sv = *(const uint4*)(h1b + ((size_t)i << 4) + (hf << 3));
        float s0 = __uint_as_float(sv.x << 16), s1 = __uint_as_float(sv.x & 0xFFFF0000u);
        float s2 = __uint_as_float(sv.y << 16), s3 = __uint_as_float(sv.y & 0xFFFF0000u);
        float s4 = __uint_as_float(sv.z << 16), s5 = __uint_as_float(sv.z & 0xFFFF0000u);
        float s6 = __uint_as_float(sv.w << 16), s7 = __uint_as_float(sv.w & 0xFFFF0000u);
        int f0 = hf * 8;
        float r0 = fmaxf(di * (a0 + s0) + b1[f0 + 0], 0.f);
        float r1 = fmaxf(di * (a1 + s1) + b1[f0 + 1], 0.f);
        float r2 = fmaxf(di * (a2 + s2) + b1[f0 + 2], 0.f);
        float r3 = fmaxf(di * (a3 + s3) + b1[f0 + 3], 0.f);
        float r4 = fmaxf(di * (a4 + s4) + b1[f0 + 4], 0.f);
        float r5 = fmaxf(di * (a5 + s5) + b1[f0 + 5], 0.f);
        float r6 = fmaxf(di * (a6 + s6) + b1[f0 + 6], 0.f);
        float r7 = fmaxf(di * (a7 + s7) + b1[f0 + 7], 0.f);
        float p0 = r0 * W2[(f0 + 0) * 2] + r1 * W2[(f0 + 1) * 2] +
                   r2 * W2[(f0 + 2) * 2] + r3 * W2[(f0 + 3) * 2] +
                   r4 * W2[(f0 + 4) * 2] + r5 * W2[(f0 + 5) * 2] +
                   r6 * W2[(f0 + 6) * 2] + r7 * W2[(f0 + 7) * 2];
        float p1 = r0 * W2[(f0 + 0) * 2 + 1] + r1 * W2[(f0 + 1) * 2 + 1] +
                   r2 * W2[(f0 + 2) * 2 + 1] + r3 * W2[(f0 + 3) * 2 + 1] +
                   r4 * W2[(f0 + 4) * 2 + 1] + r5 * W2[(f0 + 5) * 2 + 1] +
                   r6 * W2[(f0 + 6) * 2 + 1] + r7 * W2[(f0 + 7) * 2 + 1];
        p0 += __shfl_xor(p0, 1, 2);
        p1 += __shfl_xor(p1, 1, 2);
        if (hf == 0) {
            float2 hv;
            hv.x = di * p0;
            hv.y = di * p1;
            *(float2*)(h2b + (size_t)i * 2) = hv;
        }
    }
}

// gather2: 4 lanes/node, 2x unrolled MLP; o = di*(sum h2b[src] + h2b[i]) + b2;
// log_softmax.
__global__ __launch_bounds__(256) void k_gather2(const int* __restrict__ row_start,
                                                 const int* __restrict__ csr_src,
                                                 const float* __restrict__ dinv,
                                                 const float* __restrict__ h2b,
                                                 const float* __restrict__ b2,
                                                 float* __restrict__ out) {
    int t = threadIdx.x;
    int i = blockIdx.x * 64 + (t >> 2);
    int l = t & 3;
    int start = row_start[i];
    int end = row_start[i + 1];
    float di = dinv[i];
    float o0 = 0.f, o1 = 0.f;
    int e = start + l;
    for (; e + 4 < end; e += 8) {
        int s1 = csr_src[e];
        int s2 = csr_src[e + 4];
        float2 hv1 = *(const float2*)(h2b + (size_t)s1 * 2);
        float2 hv2 = *(const float2*)(h2b + (size_t)s2 * 2);
        o0 += hv1.x + hv2.x;
        o1 += hv1.y + hv2.y;
    }
    for (; e < end; e += 4) {
        int src = csr_src[e];
        float2 hv = *(const float2*)(h2b + (size_t)src * 2);
        o0 += hv.x;
        o1 += hv.y;
    }
    o0 += __shfl_xor(o0, 1, 4);
    o1 += __shfl_xor(o1, 1, 4);
    o0 += __shfl_xor(o0, 2, 4);
    o1 += __shfl_xor(o1, 2, 4);
    if (l == 0) {
        float2 hs = *(const float2*)(h2b + (size_t)i * 2);
        float f0 = di * (o0 + hs.x) + b2[0];
        float f1 = di * (o1 + hs.y) + b2[1];
        float m = fmaxf(f0, f1);
        float lse = m + logf(expf(f0 - m) + expf(f1 - m));
        out[(size_t)i * 2 + 0] = f0 - lse;
        out[(size_t)i * 2 + 1] = f1 - lse;
    }
}

extern "C" void kernel_launch(void* const* d_in, const int* in_sizes, int n_in,
                              void* d_out, int out_size, void* d_ws, size_t ws_size,
                              hipStream_t stream) {
    const float* x  = (const float*)d_in[0];
    const void*  ei = d_in[1];
    const float* W1 = (const float*)d_in[2];
    const float* b1 = (const float*)d_in[3];
    const float* W2 = (const float*)d_in[4];
    const float* b2 = (const float*)d_in[5];

    int*            wsw       = (int*)d_ws;
    float*          dinv      = (float*)(wsw + OFF_DINV);
    int*            row_start = wsw + OFF_ROW;
    int*            bcount    = wsw + OFF_BCOUNT;
    int*            bbase     = wsw + OFF_BBASE;
    int*            histB     = wsw + OFF_HISTB;
    int*            baseB     = wsw + OFF_BASEB;
    unsigned*       ebuf      = (unsigned*)(wsw + OFF_EBUF);   // becomes csr_src
    unsigned short* h1b       = (unsigned short*)(wsw + OFF_H1B);
    float*          h2b       = (float*)(wsw + OFF_H2B);
    float*          out       = (float*)d_out;

    k_init<<<1, 512, 0, stream>>>(bcount);
    k_bhist<<<NCHUNK, 1024, 0, stream>>>(ei, bcount, histB);
    k_bscan<<<1, 512, 0, stream>>>(bcount, bbase, row_start);
    k_colscan<<<512, 256, 0, stream>>>(histB, bbase, baseB);
    k_bscatter<<<NCHUNK, 1024, 0, stream>>>(ei, histB, baseB, ebuf);
    k_bsort<<<NB, 1024, 0, stream>>>(ebuf, bbase, row_start, dinv);
    k_gemm1<<<(N_NODES + 63) / 64, 256, 0, stream>>>(x, W1, dinv, h1b);
    k_gather1<<<N_NODES / 16, 256, 0, stream>>>(row_start, (const int*)ebuf, dinv, h1b, b1, W2, h2b);
    k_gather2<<<N_NODES / 64, 256, 0, stream>>>(row_start, (const int*)ebuf, dinv, h2b, b2, out);
}